// Round 11
// baseline (277.981 us; speedup 1.0000x reference)
//
#include <hip/hip_runtime.h>
#include <hip/hip_bf16.h>

// Fused causal MHA for MI355X (gfx950).
// Round-10: attention KVBLK 32->64 (halve per-key softmax/LDS/shfl overhead,
// double MFMA clusters). Keeps paired q-tiles + XCD-local bh (FETCH 12MB).
// Workspace (48 MB): [0,8M) x_bf16 | [8,16M) Wq/Wk/Wv/Wo bf16
//   [16,24M) Q (b,h,n,d) bf16 pre-scaled 0.125*log2e | [24,32M) K (b,h,n,d)
//   [32,40M) V^T (b,h,d,n) | [40,48M) attn_out (b,n,h*dv) bf16

using bf16x8   = __attribute__((ext_vector_type(8))) __bf16;
using f32x4    = __attribute__((ext_vector_type(4))) float;
using ushort4v = __attribute__((ext_vector_type(4))) unsigned short;

__device__ __forceinline__ unsigned short f2bf(float f) {
    unsigned int u = __float_as_uint(f);
    u += 0x7FFFu + ((u >> 16) & 1u);
    return (unsigned short)(u >> 16);
}

__device__ __forceinline__ unsigned cvtpk(float lo, float hi) {
    unsigned r;
    asm("v_cvt_pk_bf16_f32 %0, %1, %2" : "=v"(r) : "v"(lo), "v"(hi));
    return r;
}

__device__ __forceinline__ void gll16(const void* g, void* l) {
    __builtin_amdgcn_global_load_lds(
        (const __attribute__((address_space(1))) void*)g,
        (__attribute__((address_space(3))) void*)l, 16, 0, 0);
}

__global__ __launch_bounds__(256) void cast_bf16_kernel(
    const float* __restrict__ in, unsigned short* __restrict__ out, int n4) {
    int i = blockIdx.x * 256 + threadIdx.x;
    if (i >= n4) return;
    float4 f = reinterpret_cast<const float4*>(in)[i];
    ushort4v o;
    o.x = f2bf(f.x); o.y = f2bf(f.y); o.z = f2bf(f.z); o.w = f2bf(f.w);
    reinterpret_cast<ushort4v*>(out)[i] = o;
}

__global__ __launch_bounds__(256) void cast_w4_kernel(
    const float* __restrict__ w0, const float* __restrict__ w1,
    const float* __restrict__ w2, const float* __restrict__ w3,
    unsigned short* __restrict__ o0, unsigned short* __restrict__ o1,
    unsigned short* __restrict__ o2, unsigned short* __restrict__ o3) {
    const int z = blockIdx.y;
    const float* in = (z == 0) ? w0 : (z == 1) ? w1 : (z == 2) ? w2 : w3;
    unsigned short* out = (z == 0) ? o0 : (z == 1) ? o1 : (z == 2) ? o2 : o3;
    int i = blockIdx.x * 256 + threadIdx.x;
    float4 f = reinterpret_cast<const float4*>(in)[i];
    ushort4v o;
    o.x = f2bf(f.x); o.y = f2bf(f.y); o.z = f2bf(f.z); o.w = f2bf(f.w);
    reinterpret_cast<ushort4v*>(out)[i] = o;
}

// ---- 128x128 GEMM core (m97 structure): C = A(MxK) * B(NxK)^T ----
__device__ __forceinline__ void gemm_core_128(
    const unsigned short* __restrict__ A, const unsigned short* __restrict__ B,
    int m0, int n0, int K,
    unsigned short* As, unsigned short* Bs, f32x4 acc[4][4]) {
    const int tid = threadIdx.x;
    const int lane = tid & 63;
    const int wid = tid >> 6;
    const int wr = wid >> 1, wc = wid & 1;
    const int l16 = lane & 15, lg = lane >> 4;

#pragma unroll
    for (int i = 0; i < 4; i++)
#pragma unroll
        for (int j = 0; j < 4; j++) acc[i][j] = f32x4{0.f, 0.f, 0.f, 0.f};

    const int srow = lane >> 2;
    const int scol = (lane & 3) * 8;
    const unsigned short* Ab0 = &A[(size_t)(m0 + wid * 16 + srow) * K + scol];
    const unsigned short* Ab1 = &A[(size_t)(m0 + 64 + wid * 16 + srow) * K + scol];
    const unsigned short* Bb0 = &B[(size_t)(n0 + wid * 16 + srow) * K + scol];
    const unsigned short* Bb1 = &B[(size_t)(n0 + 64 + wid * 16 + srow) * K + scol];
    unsigned short* AsW0 = As + (wid * 16) * 32;
    unsigned short* AsW1 = As + (64 + wid * 16) * 32;
    unsigned short* BsW0 = Bs + (wid * 16) * 32;
    unsigned short* BsW1 = Bs + (64 + wid * 16) * 32;

    for (int k0 = 0; k0 < K; k0 += 32) {
        __syncthreads();
        gll16(Ab0 + k0, AsW0);
        gll16(Ab1 + k0, AsW1);
        gll16(Bb0 + k0, BsW0);
        gll16(Bb1 + k0, BsW1);
        __syncthreads();
        bf16x8 af[4], bfr[4];
#pragma unroll
        for (int i = 0; i < 4; i++)
            af[i] = *reinterpret_cast<const bf16x8*>(&As[(64 * wr + 16 * i + l16) * 32 + 8 * lg]);
#pragma unroll
        for (int j = 0; j < 4; j++)
            bfr[j] = *reinterpret_cast<const bf16x8*>(&Bs[(64 * wc + 16 * j + l16) * 32 + 8 * lg]);
#pragma unroll
        for (int i = 0; i < 4; i++)
#pragma unroll
            for (int j = 0; j < 4; j++)
                acc[i][j] = __builtin_amdgcn_mfma_f32_16x16x32_bf16(af[i], bfr[j], acc[i][j], 0, 0, 0);
    }
}

// ---- 128x64 GEMM core (out-proj) ----
__device__ __forceinline__ void gemm_core_128x64(
    const unsigned short* __restrict__ A, const unsigned short* __restrict__ B,
    int m0, int n0, int K,
    unsigned short* As, unsigned short* Bs, f32x4 acc[4][2]) {
    const int tid = threadIdx.x;
    const int lane = tid & 63;
    const int wid = tid >> 6;
    const int wr = wid >> 1, wc = wid & 1;
    const int l16 = lane & 15, lg = lane >> 4;

#pragma unroll
    for (int i = 0; i < 4; i++)
#pragma unroll
        for (int j = 0; j < 2; j++) acc[i][j] = f32x4{0.f, 0.f, 0.f, 0.f};

    const int srow = lane >> 2;
    const int scol = (lane & 3) * 8;
    const unsigned short* Ab0 = &A[(size_t)(m0 + wid * 16 + srow) * K + scol];
    const unsigned short* Ab1 = &A[(size_t)(m0 + 64 + wid * 16 + srow) * K + scol];
    const unsigned short* Bb0 = &B[(size_t)(n0 + wid * 16 + srow) * K + scol];
    unsigned short* AsW0 = As + (wid * 16) * 32;
    unsigned short* AsW1 = As + (64 + wid * 16) * 32;
    unsigned short* BsW0 = Bs + (wid * 16) * 32;

    for (int k0 = 0; k0 < K; k0 += 32) {
        __syncthreads();
        gll16(Ab0 + k0, AsW0);
        gll16(Ab1 + k0, AsW1);
        gll16(Bb0 + k0, BsW0);
        __syncthreads();
        bf16x8 af[4], bfr[2];
#pragma unroll
        for (int i = 0; i < 4; i++)
            af[i] = *reinterpret_cast<const bf16x8*>(&As[(64 * wr + 16 * i + l16) * 32 + 8 * lg]);
#pragma unroll
        for (int j = 0; j < 2; j++)
            bfr[j] = *reinterpret_cast<const bf16x8*>(&Bs[(32 * wc + 16 * j + l16) * 32 + 8 * lg]);
#pragma unroll
        for (int i = 0; i < 4; i++)
#pragma unroll
            for (int j = 0; j < 2; j++)
                acc[i][j] = __builtin_amdgcn_mfma_f32_16x16x32_bf16(af[i], bfr[j], acc[i][j], 0, 0, 0);
    }
}

// ---- QKV projection: z=0 -> Q (scaled 0.125*log2e), z=1 -> K, z=2 -> V^T ----
__global__ __launch_bounds__(256) void gemm_qkv_kernel(
    const unsigned short* __restrict__ xbf,
    const unsigned short* __restrict__ wq, const unsigned short* __restrict__ wk,
    const unsigned short* __restrict__ wv,
    const float* __restrict__ bq, const float* __restrict__ bk, const float* __restrict__ bv,
    unsigned short* __restrict__ q_ws, unsigned short* __restrict__ k_ws,
    unsigned short* __restrict__ vt_ws) {
    __shared__ __align__(16) unsigned short As[128 * 32];
    __shared__ __align__(16) unsigned short Bs[128 * 32];
    const int z = blockIdx.z;
    const unsigned short* W = (z == 0) ? wq : ((z == 1) ? wk : wv);
    const float* bias = (z == 0) ? bq : ((z == 1) ? bk : bv);
    const float scale = (z == 0) ? 0.125f * 1.44269504f : 1.0f;
    const int m0 = blockIdx.y * 128;
    const int n0 = blockIdx.x * 128;

    f32x4 acc[4][4];
    gemm_core_128(xbf, W, m0, n0, 1024, As, Bs, acc);

    const int tid = threadIdx.x;
    const int lane = tid & 63;
    const int wid = tid >> 6;
    const int wr = wid >> 1, wc = wid & 1;
    const int l16 = lane & 15, lg = lane >> 4;

#pragma unroll
    for (int j = 0; j < 4; j++) {
        const int c = n0 + 64 * wc + 16 * j + l16;
        const float bc = bias[c];
        const int h = c >> 6, d = c & 63;
#pragma unroll
        for (int i = 0; i < 4; i++) {
            const int mb = m0 + 64 * wr + 16 * i + 4 * lg;
            if (z < 2) {
                unsigned short* dst = (z == 0) ? q_ws : k_ws;
#pragma unroll
                for (int r = 0; r < 4; r++) {
                    int m = mb + r;
                    int b = m >> 11, n = m & 2047;
                    float v = (acc[i][j][r] + bc) * scale;
                    dst[(((b * 16 + h) * 2048 + n) << 6) + d] = f2bf(v);
                }
            } else {
                int b = mb >> 11, n = mb & 2047;
                ushort4v pk;
                pk.x = f2bf(acc[i][j][0] + bc);
                pk.y = f2bf(acc[i][j][1] + bc);
                pk.z = f2bf(acc[i][j][2] + bc);
                pk.w = f2bf(acc[i][j][3] + bc);
                *reinterpret_cast<ushort4v*>(&vt_ws[((b * 16 + h) * 64 + d) * 2048 + n]) = pk;
            }
        }
    }
}

// ---- Flash attention v6: paired q-tiles, XCD-local bh, KVBLK=64 ----
// bid 0..511: xcd = bid&7, idx = bid>>3; bh = xcd*4 + (idx>>4);
// p = (idx&15)*4 + wid -> q-tiles (p, 127-p). KV tiles of 64.
__global__ __launch_bounds__(256, 2) void attn_kernel(
    const unsigned short* __restrict__ q_ws, const unsigned short* __restrict__ k_ws,
    const unsigned short* __restrict__ vt_ws, unsigned short* __restrict__ attn_out) {
    __shared__ __align__(16) unsigned short P_lds[4][2][16][72];   // wave, slot, q-row, k(64+pad)
    const int tid = threadIdx.x;
    const int wid = tid >> 6, lane = tid & 63;
    const int l16 = lane & 15, lg = lane >> 4;
    const int bid = blockIdx.x;               // 0..511
    const int xcd = bid & 7, idx = bid >> 3;  // idx 0..63
    const int bh = xcd * 4 + (idx >> 4);      // 4 bh per XCD -> K/V L2-resident
    const int p = ((idx & 15) << 2) + wid;    // 0..63
    const int qA0 = p << 4;                   // 0..1008
    const int qB0 = 2032 - (p << 4);          // 2032..1024
    const unsigned short* qb = q_ws + bh * (2048 * 64);
    const unsigned short* kb = k_ws + bh * (2048 * 64);
    const unsigned short* vb = vt_ws + bh * (64 * 2048);

    // Q fragments (hoisted; pre-scaled). Operand layout [q=l16][d=8lg+j].
    bf16x8 aqA0 = *reinterpret_cast<const bf16x8*>(&qb[(qA0 + l16) * 64 + 8 * lg]);
    bf16x8 aqA1 = *reinterpret_cast<const bf16x8*>(&qb[(qA0 + l16) * 64 + 32 + 8 * lg]);
    bf16x8 aqB0 = *reinterpret_cast<const bf16x8*>(&qb[(qB0 + l16) * 64 + 8 * lg]);
    bf16x8 aqB1 = *reinterpret_cast<const bf16x8*>(&qb[(qB0 + l16) * 64 + 32 + 8 * lg]);

    f32x4 oA[4], oB[4];
#pragma unroll
    for (int j = 0; j < 4; j++) { oA[j] = f32x4{0.f, 0.f, 0.f, 0.f}; oB[j] = f32x4{0.f, 0.f, 0.f, 0.f}; }
    float mA = -1e30f, lA = 0.f, mB = -1e30f, lB = 0.f;

    const int kvEnd = qB0 + 16;
    for (int kv0 = 0; kv0 < kvEnd; kv0 += 64) {
        // K: 4 subtiles of 16 rows, 2 d-halves each (32 VGPR)
        bf16x8 kf[4][2];
#pragma unroll
        for (int s = 0; s < 4; s++) {
            const unsigned short* kr = &kb[(kv0 + 16 * s + l16) * 64 + 8 * lg];
            kf[s][0] = *reinterpret_cast<const bf16x8*>(kr);
            kf[s][1] = *reinterpret_cast<const bf16x8*>(kr + 32);
        }
        // V^T: 4 d-groups x 2 k-halves (32 VGPR)
        bf16x8 vf[4][2];
#pragma unroll
        for (int j = 0; j < 4; j++) {
            const unsigned short* vr = &vb[(16 * j + l16) * 2048 + kv0 + 8 * lg];
            vf[j][0] = *reinterpret_cast<const bf16x8*>(vr);
            vf[j][1] = *reinterpret_cast<const bf16x8*>(vr + 32);
        }

        // softmax (log2 domain) + PV over a 64-key tile for one q-tile
        auto process = [&](const bf16x8& q0f, const bf16x8& q1f, int qX0,
                           float& mX, float& lX, f32x4* o, int slot, bool diag) {
            const f32x4 z = f32x4{0.f, 0.f, 0.f, 0.f};
            f32x4 s[4];
#pragma unroll
            for (int ss = 0; ss < 4; ss++) {
                s[ss] = __builtin_amdgcn_mfma_f32_16x16x32_bf16(kf[ss][0], q0f, z, 0, 0, 0);
                s[ss] = __builtin_amdgcn_mfma_f32_16x16x32_bf16(kf[ss][1], q1f, s[ss], 0, 0, 0);
            }
            if (diag) {
                const int qrow = qX0 + l16;
#pragma unroll
                for (int ss = 0; ss < 4; ss++) {
                    const int kbase = kv0 + 16 * ss + 4 * lg;
#pragma unroll
                    for (int r = 0; r < 4; r++)
                        if (kbase + r > qrow) s[ss][r] = -1e30f;
                }
            }
            float mx = -1e30f;
#pragma unroll
            for (int ss = 0; ss < 4; ss++)
                mx = fmaxf(mx, fmaxf(fmaxf(s[ss][0], s[ss][1]), fmaxf(s[ss][2], s[ss][3])));
            mx = fmaxf(mx, __shfl_xor(mx, 16));
            mx = fmaxf(mx, __shfl_xor(mx, 32));
            if (!__all(mx <= mX + 8.0f)) {      // defer-max (T13)
                const float mnew = fmaxf(mX, mx);
                const float sf = __builtin_amdgcn_exp2f(mX - mnew);
                mX = mnew;
                lX *= sf;
                float sfT[4];
#pragma unroll
                for (int r = 0; r < 4; r++) sfT[r] = __shfl(sf, 4 * lg + r);
#pragma unroll
                for (int j = 0; j < 4; j++) {
                    o[j][0] *= sfT[0]; o[j][1] *= sfT[1];
                    o[j][2] *= sfT[2]; o[j][3] *= sfT[3];
                }
            }
            float pr[4][4];
#pragma unroll
            for (int ss = 0; ss < 4; ss++)
#pragma unroll
                for (int r = 0; r < 4; r++)
                    pr[ss][r] = __builtin_amdgcn_exp2f(s[ss][r] - mX);
            float sum = 0.f;
#pragma unroll
            for (int ss = 0; ss < 4; ss++)
                sum += (pr[ss][0] + pr[ss][1]) + (pr[ss][2] + pr[ss][3]);
            sum += __shfl_xor(sum, 16);
            sum += __shfl_xor(sum, 32);
            lX += sum;
            // P -> LDS: row q=l16, keys 16*ss+4lg..+3 (covers 0..63 per row)
#pragma unroll
            for (int ss = 0; ss < 4; ss++) {
                uint2 w = make_uint2(cvtpk(pr[ss][0], pr[ss][1]), cvtpk(pr[ss][2], pr[ss][3]));
                *reinterpret_cast<uint2*>(&P_lds[wid][slot][l16][16 * ss + 4 * lg]) = w;
            }
            bf16x8 pf0 = *reinterpret_cast<const bf16x8*>(&P_lds[wid][slot][l16][8 * lg]);
            bf16x8 pf1 = *reinterpret_cast<const bf16x8*>(&P_lds[wid][slot][l16][32 + 8 * lg]);
#pragma unroll
            for (int j = 0; j < 4; j++) {
                o[j] = __builtin_amdgcn_mfma_f32_16x16x32_bf16(pf0, vf[j][0], o[j], 0, 0, 0);
                o[j] = __builtin_amdgcn_mfma_f32_16x16x32_bf16(pf1, vf[j][1], o[j], 0, 0, 0);
            }
        };
        const bool diagB = (kv0 + 64 >= kvEnd);
        process(aqB0, aqB1, qB0, mB, lB, oB, 1, diagB);
        const bool actA = kv0 < qA0 + 16;
        if (actA) {
            const bool diagA = (kv0 + 64 >= qA0 + 16);
            process(aqA0, aqA1, qA0, mA, lA, oA, 0, diagA);
        }
    }

    // epilogue
    const int b = bh >> 4, h = bh & 15;
    auto epi = [&](int qX0, float lX, f32x4* o) {
        float inv[4];
#pragma unroll
        for (int r = 0; r < 4; r++) inv[r] = 1.0f / __shfl(lX, 4 * lg + r);
#pragma unroll
        for (int j = 0; j < 4; j++)
#pragma unroll
            for (int r = 0; r < 4; r++) {
                int n = qX0 + 4 * lg + r;
                attn_out[(size_t)(b * 2048 + n) * 1024 + h * 64 + 16 * j + l16] =
                    f2bf(o[j][r] * inv[r]);
            }
    };
    epi(qA0, lA, oA);
    epi(qB0, lB, oB);
}

// ---- output projection: out = attn_out @ Wo^T (f32 out, no bias) ----
__global__ __launch_bounds__(256) void gemm_out_kernel(
    const unsigned short* __restrict__ abf, const unsigned short* __restrict__ wo,
    float* __restrict__ out) {
    __shared__ __align__(16) unsigned short As[128 * 32];
    __shared__ __align__(16) unsigned short Bs[64 * 32];
    const int m0 = blockIdx.y * 128;
    const int n0 = blockIdx.x * 64;
    f32x4 acc[4][2];
    gemm_core_128x64(abf, wo, m0, n0, 1024, As, Bs, acc);

    const int tid = threadIdx.x;
    const int lane = tid & 63;
    const int wid = tid >> 6;
    const int wr = wid >> 1, wc = wid & 1;
    const int l16 = lane & 15, lg = lane >> 4;
#pragma unroll
    for (int j = 0; j < 2; j++) {
        const int c = n0 + 32 * wc + 16 * j + l16;
#pragma unroll
        for (int i = 0; i < 4; i++) {
#pragma unroll
            for (int r = 0; r < 4; r++) {
                int m = m0 + 64 * wr + 16 * i + 4 * lg + r;
                out[(size_t)m * 1024 + c] = acc[i][j][r];
            }
        }
    }
}

extern "C" void kernel_launch(void* const* d_in, const int* in_sizes, int n_in,
                              void* d_out, int out_size, void* d_ws, size_t ws_size,
                              hipStream_t stream) {
    const float* x  = (const float*)d_in[0];
    const float* Wq = (const float*)d_in[1];
    const float* bq = (const float*)d_in[2];
    const float* Wk = (const float*)d_in[3];
    const float* bk = (const float*)d_in[4];
    const float* Wv = (const float*)d_in[5];
    const float* bv = (const float*)d_in[6];
    const float* Wo = (const float*)d_in[7];
    float* out = (float*)d_out;

    char* ws = (char*)d_ws;
    unsigned short* xbf  = (unsigned short*)(ws);
    unsigned short* wqbf = (unsigned short*)(ws + (8u  << 20));
    unsigned short* wkbf = (unsigned short*)(ws + (10u << 20));
    unsigned short* wvbf = (unsigned short*)(ws + (12u << 20));
    unsigned short* wobf = (unsigned short*)(ws + (14u << 20));
    unsigned short* qws  = (unsigned short*)(ws + (16u << 20));
    unsigned short* kws  = (unsigned short*)(ws + (24u << 20));
    unsigned short* vtws = (unsigned short*)(ws + (32u << 20));
    unsigned short* aows = (unsigned short*)(ws + (40u << 20));

    cast_bf16_kernel<<<4096, 256, 0, stream>>>(x, xbf, 4096 * 1024 / 4);
    cast_w4_kernel<<<dim3(1024, 4), 256, 0, stream>>>(
        Wq, Wk, Wv, Wo, wqbf, wkbf, wvbf, wobf);

    // QKV: 128x128 tiles -> (8, 32, 3) = 768 blocks (~3/CU, m97 structure)
    gemm_qkv_kernel<<<dim3(8, 32, 3), 256, 0, stream>>>(
        xbf, wqbf, wkbf, wvbf, bq, bk, bv, qws, kws, vtws);

    // attention: 512 blocks x 4 waves, paired q-tiles, KVBLK=64, XCD-local bh
    attn_kernel<<<512, 256, 0, stream>>>(qws, kws, vtws, aows);

    // out projection: 128x64 tiles -> (16, 32) = 512 blocks (2/CU)
    gemm_out_kernel<<<dim3(16, 32), 256, 0, stream>>>(aows, wobf, out);
}